// Round 2
// baseline (882.533 us; speedup 1.0000x reference)
//
#include <hip/hip_runtime.h>

// ===================== helpers =====================

__device__ __forceinline__ float bnscale(float g){ return g / sqrtf(1.0f + 1e-5f); }

__device__ __forceinline__ float conv_feat6(float p0,float p1,float p2,float p3,float p4,float p5,
                                            float w0,float w1,float w2,float w3,float w4,float w5,
                                            float sc,float bs){
    float y = p0*w0;
    y = fmaf(p1,w1,y); y = fmaf(p2,w2,y); y = fmaf(p3,w3,y);
    y = fmaf(p4,w4,y); y = fmaf(p5,w5,y);
    return fmaxf(fmaf(y,sc,bs), 0.0f);
}

// FPS distance: matches jnp.sum((p-c)**2, -1) left-to-right, NO contraction
// (contract-off also guarantees every inline site compiles identically).
__device__ __forceinline__ float fpsdist(float dx,float dy,float dz){
    #pragma clang fp contract(off)
    return (dx*dx + dy*dy) + dz*dz;
}

// expanded-form squared distance, matches square_distance():
// d = (-2*dot + |q|^2) + |p|^2, dot/sumsq left-to-right, NO contraction.
__device__ __forceinline__ float sumsq3(float x,float y,float z){
    #pragma clang fp contract(off)
    return (x*x + y*y) + z*z;
}
__device__ __forceinline__ float sqdist3(float qx,float qy,float qz,float qs,
                                         float px,float py,float pz){
    #pragma clang fp contract(off)
    {
        float dot = (qx*px + qy*py) + qz*pz;
        float pn  = (px*px + py*py) + pz*pz;
        return (-2.0f*dot + qs) + pn;
    }
}

// pack (dist,idx) into sortable u64: ascending u64 == ascending (dist, idx) lexicographic
__device__ __forceinline__ unsigned long long packdi(float d, unsigned int idx){
    unsigned int u = __float_as_uint(d);
    unsigned int msk = (unsigned int)((int)u >> 31);
    u ^= (msk | 0x80000000u);
    return ((unsigned long long)u << 32) | (unsigned long long)idx;
}

__device__ __forceinline__ unsigned long long u64min(unsigned long long a, unsigned long long b){
    return a < b ? a : b;
}

__device__ __forceinline__ unsigned long long u64_shfl_down(unsigned long long v, int off){
    unsigned int lo = (unsigned int)v, hi = (unsigned int)(v >> 32);
    lo = __shfl_down(lo, off, 64);
    hi = __shfl_down(hi, off, 64);
    return ((unsigned long long)hi << 32) | (unsigned long long)lo;
}

__device__ __forceinline__ unsigned long long u64_bcast0(unsigned long long v){
    unsigned int lo = (unsigned int)v, hi = (unsigned int)(v >> 32);
    lo = __shfl(lo, 0, 64);
    hi = __shfl(hi, 0, 64);
    return ((unsigned long long)hi << 32) | (unsigned long long)lo;
}

// ===================== k_center =====================
__global__ __launch_bounds__(256) void k_center(const float* __restrict__ xyz,
                                                float* __restrict__ center,
                                                float* __restrict__ out){
    int b = blockIdx.x, t = threadIdx.x;
    __shared__ float sb[256][3];
    float sx=0.f, sy=0.f, sz=0.f;
    for (int n = t; n < 16384; n += 256){
        const float* p = xyz + ((size_t)b*16384 + n)*3;
        sx += p[0]; sy += p[1]; sz += p[2];
    }
    sb[t][0]=sx; sb[t][1]=sy; sb[t][2]=sz;
    __syncthreads();
    for (int off=128; off; off>>=1){
        if (t < off){ sb[t][0]+=sb[t+off][0]; sb[t][1]+=sb[t+off][1]; sb[t][2]+=sb[t+off][2]; }
        __syncthreads();
    }
    if (t < 3){
        float c = sb[0][t] / 16384.0f;
        center[b*3+t] = c;
        out[b*3+t] = c;      // output 0: center (32,3)
    }
}

// ===================== k_fps =====================
// Farthest point sampling, one block per batch. Matches lax.scan semantics:
// idx[0]=0; idx[it] = argmax(dist) after it min-updates. Ties -> lowest index.
template<int N, int NPOINT, int NTH, int PPT, bool SUB>
__global__ __launch_bounds__(NTH) void k_fps(const float* __restrict__ src,
                                             const float* __restrict__ center,
                                             int* __restrict__ idx_out){
    static_assert(N == NTH*PPT, "bad fps cfg");
    constexpr int NW = NTH/64;
    int b = blockIdx.x, t = threadIdx.x;
    __shared__ float s_c[3];
    __shared__ int   s_far;
    __shared__ float s_wv[NW];
    __shared__ int   s_wi[NW];

    float cx0=0.f, cy0=0.f, cz0=0.f;
    if constexpr (SUB){
        cx0 = center[b*3+0]; cy0 = center[b*3+1]; cz0 = center[b*3+2];
    }
    float px[PPT], py[PPT], pz[PPT], dist[PPT];
    #pragma unroll
    for (int i=0;i<PPT;i++){
        int p = t + i*NTH;
        const float* sp = src + ((size_t)b*N + p)*3;
        px[i]=sp[0]-cx0; py[i]=sp[1]-cy0; pz[i]=sp[2]-cz0;
        dist[i]=1e10f;
    }
    if (t==0){ idx_out[b*NPOINT] = 0; s_far = 0; }
    __syncthreads();

    for (int it=1; it<NPOINT; ++it){
        if (t==0){
            const float* sp = src + ((size_t)b*N + s_far)*3;
            s_c[0]=sp[0]-cx0; s_c[1]=sp[1]-cy0; s_c[2]=sp[2]-cz0;
        }
        __syncthreads();
        float cx=s_c[0], cy=s_c[1], cz=s_c[2];
        float bv=-1.0f; int bi=0;
        #pragma unroll
        for (int i=0;i<PPT;i++){
            float d = fpsdist(px[i]-cx, py[i]-cy, pz[i]-cz);
            float nd = fminf(dist[i], d);
            dist[i] = nd;
            if (nd > bv){ bv = nd; bi = t + i*NTH; }   // strict > keeps lowest index in-thread
        }
        // wave argmax (ties -> lowest index)
        #pragma unroll
        for (int off=32; off>=1; off>>=1){
            float ov = __shfl_down(bv, off, 64);
            int   oi = __shfl_down(bi, off, 64);
            if (ov > bv || (ov == bv && oi < bi)){ bv=ov; bi=oi; }
        }
        if ((t&63)==0){ s_wv[t>>6]=bv; s_wi[t>>6]=bi; }
        __syncthreads();
        if (t==0){
            float v = s_wv[0]; int xi = s_wi[0];
            #pragma unroll
            for (int w2=1; w2<NW; ++w2){
                if (s_wv[w2] > v || (s_wv[w2]==v && s_wi[w2] < xi)){ v=s_wv[w2]; xi=s_wi[w2]; }
            }
            s_far = xi;
            idx_out[b*NPOINT + it] = xi;
        }
    }
}

// ===================== k_gather1 =====================
// one wave per (b,s): new_xyz1 (centered coords) + conv feature of FPS point
__global__ __launch_bounds__(64) void k_gather1(const float* __restrict__ xyz,
                                                const float* __restrict__ f,
                                                const float* __restrict__ center,
                                                const float* __restrict__ conv1_w,
                                                const float* __restrict__ bn1_g,
                                                const float* __restrict__ bn1_b,
                                                const int* __restrict__ fps_idx,
                                                float* __restrict__ new_xyz,
                                                float* __restrict__ np_feat){
    int q = blockIdx.x; int b = q>>7, s = q&127;
    int o = threadIdx.x;
    int idx = fps_idx[b*128+s];
    const float* xp = xyz + ((size_t)b*16384 + idx)*3;
    const float* fp = f   + ((size_t)b*16384 + idx)*3;
    float p0 = xp[0]-center[b*3+0], p1 = xp[1]-center[b*3+1], p2 = xp[2]-center[b*3+2];
    float p3 = fp[0], p4 = fp[1], p5 = fp[2];
    const float* w = conv1_w + o*6;
    float v = conv_feat6(p0,p1,p2,p3,p4,p5, w[0],w[1],w[2],w[3],w[4],w[5],
                         bnscale(bn1_g[o]), bn1_b[o]);
    np_feat[((size_t)b*128 + s)*64 + o] = v;
    if (o < 3){
        float pc = (o==0)?p0:((o==1)?p1:p2);
        new_xyz[((size_t)b*128 + s)*3 + o] = pc;
    }
}

// ===================== k_knn1 =====================
// one block per query (b,s). 256 chunk-minima in LDS; 32 rounds of
// global-min + threshold-excluded chunk rescan (selection is ascending in
// packed (d,idx), so "packed <= last_selected" excludes exactly the chosen set).
__global__ __launch_bounds__(256) void k_knn1(const float* __restrict__ xyz,
                                              const float* __restrict__ center,
                                              const float* __restrict__ new_xyz,
                                              int* __restrict__ knn_idx){
    int q = blockIdx.x; int b = q>>7;
    int t = threadIdx.x;
    __shared__ unsigned long long scmin[256];

    float cx = center[b*3+0], cy = center[b*3+1], cz = center[b*3+2];
    float qx = new_xyz[(size_t)q*3+0], qy = new_xyz[(size_t)q*3+1], qz = new_xyz[(size_t)q*3+2];
    float qs = sumsq3(qx,qy,qz);
    const float* xb = xyz + (size_t)b*16384*3;

    // phase 1: chunk t = points {t + 256*i}
    unsigned long long m = 0xFFFFFFFFFFFFFFFFull;
    for (int i=0;i<64;i++){
        int n = t + (i<<8);
        const float* p = xb + (size_t)n*3;
        float px = p[0]-cx, py = p[1]-cy, pz = p[2]-cz;
        float d = sqdist3(qx,qy,qz,qs,px,py,pz);
        m = u64min(m, packdi(d, (unsigned)n));
    }
    scmin[t] = m;
    __syncthreads();
    if (t >= 64) return;        // wave 0 does the rounds

    for (int r=0; r<32; ++r){
        unsigned long long mm = u64min(u64min(scmin[t], scmin[t+64]),
                                       u64min(scmin[t+128], scmin[t+192]));
        #pragma unroll
        for (int off=32; off>=1; off>>=1) mm = u64min(mm, u64_shfl_down(mm, off));
        unsigned long long win = u64_bcast0(mm);
        unsigned int widx = (unsigned int)(win & 0xFFFFFFFFull);
        if (t==0) knn_idx[(size_t)q*32 + r] = (int)widx;
        int c = (int)(widx & 255u);
        // rescan chunk c excluding everything already selected (packed <= win)
        int n = c + (t<<8);
        const float* p = xb + (size_t)n*3;
        float px = p[0]-cx, py = p[1]-cy, pz = p[2]-cz;
        float d = sqdist3(qx,qy,qz,qs,px,py,pz);
        unsigned long long pk = packdi(d, (unsigned)n);
        if (pk <= win) pk = 0xFFFFFFFFFFFFFFFFull;
        #pragma unroll
        for (int off=32; off>=1; off>>=1) pk = u64min(pk, u64_shfl_down(pk, off));
        if (t==0) scmin[c] = pk;
    }
}

// ===================== k_gather2 =====================
__global__ __launch_bounds__(64) void k_gather2(const float* __restrict__ new_xyz1,
                                                const float* __restrict__ feat,
                                                const int* __restrict__ fps2,
                                                float* __restrict__ new_xyz2,
                                                float* __restrict__ np2){
    int q = blockIdx.x; int b = q>>5, s = q&31;
    int o = threadIdx.x;
    int idx = fps2[b*32+s];
    np2[((size_t)b*32 + s)*64 + o] = feat[((size_t)b*128 + idx)*64 + o];
    if (o < 3) new_xyz2[((size_t)b*32 + s)*3 + o] = new_xyz1[((size_t)b*128 + idx)*3 + o];
}

// ===================== k_knn2 =====================
// one wave per query; 128 candidate points -> 2 per lane; 16 extract-min rounds
__global__ __launch_bounds__(256) void k_knn2(const float* __restrict__ pts,   // new_xyz1 (b,128,3)
                                              const float* __restrict__ qpts,  // new_xyz2 (b,32,3)
                                              int* __restrict__ knn_idx){
    int t = threadIdx.x;
    int wid = t>>6, lane = t&63;
    int q = blockIdx.x*4 + wid;      // 0..1023
    int b = q>>5;
    float qx = qpts[(size_t)q*3+0], qy = qpts[(size_t)q*3+1], qz = qpts[(size_t)q*3+2];
    float qs = sumsq3(qx,qy,qz);
    const float* pb = pts + (size_t)b*128*3;

    unsigned long long p0, p1;
    {
        int n = lane;
        float px=pb[n*3+0], py=pb[n*3+1], pz=pb[n*3+2];
        p0 = packdi(sqdist3(qx,qy,qz,qs,px,py,pz), (unsigned)n);
        n = lane + 64;
        px=pb[n*3+0]; py=pb[n*3+1]; pz=pb[n*3+2];
        p1 = packdi(sqdist3(qx,qy,qz,qs,px,py,pz), (unsigned)n);
    }
    for (int r=0; r<16; ++r){
        unsigned long long mm = u64min(p0, p1);
        #pragma unroll
        for (int off=32; off>=1; off>>=1) mm = u64min(mm, u64_shfl_down(mm, off));
        unsigned long long win = u64_bcast0(mm);
        if (lane==0) knn_idx[(size_t)q*16 + r] = (int)(win & 0xFFFFFFFFull);
        if (p0 == win) p0 = 0xFFFFFFFFFFFFFFFFull;
        if (p1 == win) p1 = 0xFFFFFFFFFFFFFFFFull;
    }
}

// ===================== k_group_local =====================
// grouped MLP + maxpool. One wave per query, lane = output channel.
// y[o] = sum_d (g[d]-np[d])*W[o,d] + sum_d np[d]*W[o,64+d];  out = max_k relu(bn(y))
template<int K, int NQ, int NSRC, bool RECOMP>
__global__ __launch_bounds__(256) void k_group_local(
    const float* __restrict__ xyz, const float* __restrict__ f, const float* __restrict__ center,
    const float* __restrict__ conv1_w, const float* __restrict__ bn1_g, const float* __restrict__ bn1_b,
    const float* __restrict__ src_feat,
    const int* __restrict__ knn_idx, const float* __restrict__ np_feat,
    const float* __restrict__ w, const float* __restrict__ g, const float* __restrict__ bb,
    float* __restrict__ out)
{
    __shared__ float wt[128*64];          // wt[d][o] = w[o*128+d]  (lane-indexed, conflict-free)
    __shared__ float s_sc[64], s_bs[64];
    __shared__ float cwT[6*64];           // conv weights transposed [j][o]
    __shared__ float s_csc[64], s_cbs[64];
    __shared__ float np_l[4][64];
    __shared__ float gd[4][64];

    int t = threadIdx.x;
    for (int e=t; e<8192; e+=256){ int o = e>>7, d = e&127; wt[d*64 + o] = w[e]; }
    if (t < 64){ s_sc[t] = bnscale(g[t]); s_bs[t] = bb[t]; }
    if constexpr (RECOMP){
        // FIX (round-1 bug): grid-stride so ALL 384 conv weights get staged
        // (previous `if (t<384)` with 256 threads left o>=43 uninitialized).
        for (int e=t; e<384; e+=256){ int o = e/6, j = e%6; cwT[j*64 + o] = conv1_w[e]; }
        if (t < 64){ s_csc[t] = bnscale(bn1_g[t]); s_cbs[t] = bn1_b[t]; }
    }
    __syncthreads();

    int wid = t>>6, lane = t&63;
    int q = blockIdx.x*4 + wid;
    int b = q / NQ, s = q % NQ;

    float np_o = np_feat[((size_t)b*NQ + s)*64 + lane];
    np_l[wid][lane] = np_o;

    float cx=0.f, cy=0.f, cz=0.f;
    if constexpr (RECOMP){ cx = center[b*3+0]; cy = center[b*3+1]; cz = center[b*3+2]; }

    // rep-term (constant over k)
    float C = 0.f;
    #pragma unroll
    for (int d=0; d<64; d++) C = fmaf(np_l[wid][d], wt[(64+d)*64 + lane], C);

    const int* kix = knn_idx + ((size_t)b*NQ + s)*K;
    float acc = -1e30f;
    for (int k=0; k<K; ++k){
        int idx = kix[k];
        float gv;
        if constexpr (RECOMP){
            const float* xp = xyz + ((size_t)b*16384 + idx)*3;
            const float* fp = f   + ((size_t)b*16384 + idx)*3;
            float p0 = xp[0]-cx, p1 = xp[1]-cy, p2 = xp[2]-cz;
            float p3 = fp[0], p4 = fp[1], p5 = fp[2];
            gv = conv_feat6(p0,p1,p2,p3,p4,p5,
                            cwT[0*64+lane], cwT[1*64+lane], cwT[2*64+lane],
                            cwT[3*64+lane], cwT[4*64+lane], cwT[5*64+lane],
                            s_csc[lane], s_cbs[lane]);
        } else {
            gv = src_feat[((size_t)b*NSRC + idx)*64 + lane];
        }
        gd[wid][lane] = gv - np_o;        // wave-ordered LDS: write then read below
        float y = C;
        #pragma unroll
        for (int d=0; d<64; d++) y = fmaf(gd[wid][d], wt[d*64 + lane], y);
        float v = fmaxf(fmaf(y, s_sc[lane], s_bs[lane]), 0.0f);
        acc = fmaxf(acc, v);
    }
    out[((size_t)b*NQ + s)*64 + lane] = acc;
}

// ===================== k_tail =====================
__device__ void sa_block(const float* X, float* Xout,
                         float* Q, float* E, float* XV, float* XR, float* CS,
                         const float* qk_w, const float* v_w, const float* v_b,
                         const float* t_w, const float* t_b,
                         const float* g, const float* bb, int t)
{
    // xq/xk: Q[n][o] = sum_c X[c][n]*qk_w[o][c]
    for (int e=t; e<512; e+=256){
        int n = e>>4, o = e&15;
        float y = 0.f;
        for (int c=0;c<64;c++) y = fmaf(qk_w[o*64+c], X[c*32+n], y);
        Q[n*16+o] = y;
    }
    // xv
    for (int e=t; e<2048; e+=256){
        int o = e>>5, n = e&31;
        float y = v_b[o];
        for (int c=0;c<64;c++) y = fmaf(v_w[o*64+c], X[c*32+n], y);
        XV[o*32+n] = y;
    }
    __syncthreads();
    // energy[n][m] = <Q[n], Q[m]>
    for (int e=t; e<1024; e+=256){
        int n = e>>5, m = e&31;
        float y = 0.f;
        for (int d=0;d<16;d++) y = fmaf(Q[n*16+d], Q[m*16+d], y);
        E[e] = y;
    }
    __syncthreads();
    // row softmax
    if (t < 32){
        float mx = -1e30f;
        for (int m=0;m<32;m++) mx = fmaxf(mx, E[t*32+m]);
        float sum = 0.f;
        for (int m=0;m<32;m++){ float v = expf(E[t*32+m]-mx); E[t*32+m]=v; sum += v; }
        for (int m=0;m<32;m++) E[t*32+m] = E[t*32+m] / sum;
    }
    __syncthreads();
    // column renorm
    if (t < 32){
        float cs = 0.f;
        for (int n=0;n<32;n++) cs += E[n*32+t];
        CS[t] = 1e-9f + cs;
    }
    __syncthreads();
    for (int e=t; e<1024; e+=256) E[e] = E[e] / CS[e&31];
    __syncthreads();
    // x_r[c][m] = sum_n XV[c][n]*attn[n][m]
    for (int e=t; e<2048; e+=256){
        int c = e>>5, m = e&31;
        float y = 0.f;
        for (int n=0;n<32;n++) y = fmaf(XV[c*32+n], E[n*32+m], y);
        XR[c*32+m] = y;
    }
    __syncthreads();
    // out = X + relu(bn(t_w @ (X - XR) + t_b))
    for (int e=t; e<2048; e+=256){
        int o = e>>5, n = e&31;
        float y = 0.f;
        for (int c=0;c<64;c++) y = fmaf(t_w[o*64+c], X[c*32+n]-XR[c*32+n], y);
        y += t_b[o];
        y = fmaxf(fmaf(y, bnscale(g[o]), bb[o]), 0.0f);
        Xout[e] = X[e] + y;
    }
    __syncthreads();
}

__global__ __launch_bounds__(256) void k_tail(
    const float* __restrict__ f1buf,   // (b,32,64)
    const float* st_c1_w, const float* st_bn1_g, const float* st_bn1_b,
    const float* st_c2_w, const float* st_bn2_g, const float* st_bn2_b,
    const float* sa1_qk, const float* sa1_v, const float* sa1_vb,
    const float* sa1_t, const float* sa1_tb, const float* sa1_g, const float* sa1_b,
    const float* sa2_qk, const float* sa2_v, const float* sa2_vb,
    const float* sa2_t, const float* sa2_tb, const float* sa2_g, const float* sa2_b,
    const float* fuse_w, const float* fuse_g, const float* fuse_b,
    const float* lin1_w, const float* bn6_g, const float* bn6_b,
    const float* lin2_w, const float* lin2_b,
    float* __restrict__ out)
{
    __shared__ float sm[14848];
    float* F1 = sm;            // 2048  [c][n]
    float* XA = sm + 2048;     // 2048
    float* XB = sm + 4096;     // 2048
    float* Q  = sm + 6144;     // 512
    float* E  = sm + 6656;     // 1024
    float* XV = sm + 7680;     // 2048
    float* XR = sm + 9728;     // 2048
    float* CS = sm + 11776;    // 32
    float* FO = sm + 6144;     // 8192 (reuses SA scratch after SA done)
    float* PO = sm + 14336;    // 256
    float* P2 = sm + 14592;    // 256

    int b = blockIdx.x, t = threadIdx.x;

    for (int e=t; e<2048; e+=256){ int n = e>>6, c = e&63; F1[c*32+n] = f1buf[((size_t)b*32+n)*64 + c]; }
    __syncthreads();
    // st conv1
    for (int e=t; e<2048; e+=256){
        int o = e>>5, n = e&31;
        float y = 0.f;
        for (int c=0;c<64;c++) y = fmaf(st_c1_w[o*64+c], F1[c*32+n], y);
        XA[e] = fmaxf(fmaf(y, bnscale(st_bn1_g[o]), st_bn1_b[o]), 0.0f);
    }
    __syncthreads();
    // st conv2
    for (int e=t; e<2048; e+=256){
        int o = e>>5, n = e&31;
        float y = 0.f;
        for (int c=0;c<64;c++) y = fmaf(st_c2_w[o*64+c], XA[c*32+n], y);
        XB[e] = fmaxf(fmaf(y, bnscale(st_bn2_g[o]), st_bn2_b[o]), 0.0f);
    }
    __syncthreads();
    sa_block(XB, XA, Q,E,XV,XR,CS, sa1_qk, sa1_v, sa1_vb, sa1_t, sa1_tb, sa1_g, sa1_b, t); // x1 -> XA
    sa_block(XA, XB, Q,E,XV,XR,CS, sa2_qk, sa2_v, sa2_vb, sa2_t, sa2_tb, sa2_g, sa2_b, t); // x2 -> XB
    // fuse: cat[x1;x2;f1] (192,32) -> 256, leaky_relu(bn)
    for (int e=t; e<8192; e+=256){
        int o = e>>5, n = e&31;
        const float* wr = fuse_w + o*192;
        float y = 0.f;
        for (int c=0;c<64;c++) y = fmaf(wr[c],      XA[c*32+n], y);
        for (int c=0;c<64;c++) y = fmaf(wr[64+c],   XB[c*32+n], y);
        for (int c=0;c<64;c++) y = fmaf(wr[128+c],  F1[c*32+n], y);
        float v = fmaf(y, bnscale(fuse_g[o]), fuse_b[o]);
        FO[e] = (v > 0.0f) ? v : 0.2f*v;
    }
    __syncthreads();
    // max over n
    {
        float mx = -1e30f;
        for (int n=0;n<32;n++) mx = fmaxf(mx, FO[t*32+n]);
        PO[t] = mx;
    }
    __syncthreads();
    // lin1 + bn6 + relu
    {
        const float* wr = lin1_w + t*256;
        float y = 0.f;
        for (int c=0;c<256;c++) y = fmaf(wr[c], PO[c], y);
        P2[t] = fmaxf(fmaf(y, bnscale(bn6_g[t]), bn6_b[t]), 0.0f);
    }
    __syncthreads();
    // lin2
    {
        const float* wr = lin2_w + t*256;
        float y = 0.f;
        for (int c=0;c<256;c++) y = fmaf(wr[c], P2[c], y);
        out[96 + b*256 + t] = y + lin2_b[t];
    }
}

// ===================== launch =====================
extern "C" void kernel_launch(void* const* d_in, const int* in_sizes, int n_in,
                              void* d_out, int out_size, void* d_ws, size_t ws_size,
                              hipStream_t stream)
{
    const float* xyz      = (const float*)d_in[0];
    const float* f        = (const float*)d_in[1];
    const float* conv1_w  = (const float*)d_in[2];
    const float* bn1_g    = (const float*)d_in[3];
    const float* bn1_b    = (const float*)d_in[4];
    const float* l0_w     = (const float*)d_in[5];
    const float* l0_g     = (const float*)d_in[6];
    const float* l0_b     = (const float*)d_in[7];
    const float* l1_w     = (const float*)d_in[8];
    const float* l1_g     = (const float*)d_in[9];
    const float* l1_b     = (const float*)d_in[10];
    const float* st_c1_w  = (const float*)d_in[11];
    const float* st_bn1_g = (const float*)d_in[12];
    const float* st_bn1_b = (const float*)d_in[13];
    const float* st_c2_w  = (const float*)d_in[14];
    const float* st_bn2_g = (const float*)d_in[15];
    const float* st_bn2_b = (const float*)d_in[16];
    const float* sa1_qk   = (const float*)d_in[17];
    const float* sa1_v    = (const float*)d_in[18];
    const float* sa1_vb   = (const float*)d_in[19];
    const float* sa1_t    = (const float*)d_in[20];
    const float* sa1_tb   = (const float*)d_in[21];
    const float* sa1_g    = (const float*)d_in[22];
    const float* sa1_b    = (const float*)d_in[23];
    const float* sa2_qk   = (const float*)d_in[24];
    const float* sa2_v    = (const float*)d_in[25];
    const float* sa2_vb   = (const float*)d_in[26];
    const float* sa2_t    = (const float*)d_in[27];
    const float* sa2_tb   = (const float*)d_in[28];
    const float* sa2_g    = (const float*)d_in[29];
    const float* sa2_b    = (const float*)d_in[30];
    const float* fuse_w   = (const float*)d_in[31];
    const float* fuse_g   = (const float*)d_in[32];
    const float* fuse_b   = (const float*)d_in[33];
    const float* lin1_w   = (const float*)d_in[34];
    const float* bn6_g    = (const float*)d_in[35];
    const float* bn6_b    = (const float*)d_in[36];
    const float* lin2_w   = (const float*)d_in[37];
    const float* lin2_b   = (const float*)d_in[38];
    float* out = (float*)d_out;

    float* ws = (float*)d_ws;
    float* center   = ws + 0;        // 96
    float* new_xyz1 = ws + 96;       // 12288
    float* np1      = ws + 12384;    // 262144
    float* feat     = ws + 274528;   // 262144
    float* new_xyz2 = ws + 536672;   // 3072
    float* np2      = ws + 539744;   // 65536
    float* f1       = ws + 605280;   // 65536
    int*   fps1     = (int*)(ws + 670816);  // 4096
    int*   knn1     = (int*)(ws + 674912);  // 131072
    int*   fps2     = (int*)(ws + 805984);  // 1024
    int*   knn2     = (int*)(ws + 807008);  // 16384  (end: 823392 floats ~ 3.3 MB)

    k_center<<<32, 256, 0, stream>>>(xyz, center, out);
    k_fps<16384,128,1024,16,true><<<32, 1024, 0, stream>>>(xyz, center, fps1);
    k_gather1<<<4096, 64, 0, stream>>>(xyz, f, center, conv1_w, bn1_g, bn1_b, fps1, new_xyz1, np1);
    k_knn1<<<4096, 256, 0, stream>>>(xyz, center, new_xyz1, knn1);
    k_group_local<32,128,1,true><<<1024, 256, 0, stream>>>(
        xyz, f, center, conv1_w, bn1_g, bn1_b, nullptr, knn1, np1, l0_w, l0_g, l0_b, feat);
    k_fps<128,32,128,1,false><<<32, 128, 0, stream>>>(new_xyz1, nullptr, fps2);
    k_gather2<<<1024, 64, 0, stream>>>(new_xyz1, feat, fps2, new_xyz2, np2);
    k_knn2<<<256, 256, 0, stream>>>(new_xyz1, new_xyz2, knn2);
    k_group_local<16,32,128,false><<<256, 256, 0, stream>>>(
        nullptr, nullptr, nullptr, nullptr, nullptr, nullptr, feat, knn2, np2, l1_w, l1_g, l1_b, f1);
    k_tail<<<32, 256, 0, stream>>>(f1,
        st_c1_w, st_bn1_g, st_bn1_b, st_c2_w, st_bn2_g, st_bn2_b,
        sa1_qk, sa1_v, sa1_vb, sa1_t, sa1_tb, sa1_g, sa1_b,
        sa2_qk, sa2_v, sa2_vb, sa2_t, sa2_tb, sa2_g, sa2_b,
        fuse_w, fuse_g, fuse_b, lin1_w, bn6_g, bn6_b, lin2_w, lin2_b, out);
}

// Round 3
// 763.944 us; speedup vs baseline: 1.1552x; 1.1552x over previous
//
#include <hip/hip_runtime.h>

// ===================== helpers =====================

__device__ __forceinline__ float bnscale(float g){ return g / sqrtf(1.0f + 1e-5f); }

__device__ __forceinline__ float conv_feat6(float p0,float p1,float p2,float p3,float p4,float p5,
                                            float w0,float w1,float w2,float w3,float w4,float w5,
                                            float sc,float bs){
    float y = p0*w0;
    y = fmaf(p1,w1,y); y = fmaf(p2,w2,y); y = fmaf(p3,w3,y);
    y = fmaf(p4,w4,y); y = fmaf(p5,w5,y);
    return fmaxf(fmaf(y,sc,bs), 0.0f);
}

// FPS distance: matches jnp.sum((p-c)**2, -1) left-to-right, NO contraction
__device__ __forceinline__ float fpsdist(float dx,float dy,float dz){
    #pragma clang fp contract(off)
    return (dx*dx + dy*dy) + dz*dz;
}

// square_distance(): d = (-2*dot + |q|^2) + |p|^2, left-to-right, NO contraction.
__device__ __forceinline__ float sumsq3(float x,float y,float z){
    #pragma clang fp contract(off)
    return (x*x + y*y) + z*z;
}
__device__ __forceinline__ float sqdist3(float qx,float qy,float qz,float qs,
                                         float px,float py,float pz){
    #pragma clang fp contract(off)
    {
        float dot = (qx*px + qy*py) + qz*pz;
        float pn  = (px*px + py*py) + pz*pz;
        return (-2.0f*dot + qs) + pn;
    }
}

// pack (dist,idx) into sortable u64: ascending u64 == ascending (dist, idx) lexicographic
__device__ __forceinline__ unsigned long long packdi(float d, unsigned int idx){
    unsigned int u = __float_as_uint(d);
    unsigned int msk = (unsigned int)((int)u >> 31);
    u ^= (msk | 0x80000000u);
    return ((unsigned long long)u << 32) | (unsigned long long)idx;
}

__device__ __forceinline__ unsigned long long u64min(unsigned long long a, unsigned long long b){
    return a < b ? a : b;
}

__device__ __forceinline__ unsigned long long u64_shfl_down(unsigned long long v, int off){
    unsigned int lo = (unsigned int)v, hi = (unsigned int)(v >> 32);
    lo = __shfl_down(lo, off, 64);
    hi = __shfl_down(hi, off, 64);
    return ((unsigned long long)hi << 32) | (unsigned long long)lo;
}

__device__ __forceinline__ unsigned long long u64_bcast0(unsigned long long v){
    unsigned int lo = (unsigned int)v, hi = (unsigned int)(v >> 32);
    lo = __shfl(lo, 0, 64);
    hi = __shfl(hi, 0, 64);
    return ((unsigned long long)hi << 32) | (unsigned long long)lo;
}

// ===================== k_center =====================
__global__ __launch_bounds__(256) void k_center(const float* __restrict__ xyz,
                                                float* __restrict__ center,
                                                float* __restrict__ out){
    int b = blockIdx.x, t = threadIdx.x;
    __shared__ float sb[256][3];
    float sx=0.f, sy=0.f, sz=0.f;
    for (int n = t; n < 16384; n += 256){
        const float* p = xyz + ((size_t)b*16384 + n)*3;
        sx += p[0]; sy += p[1]; sz += p[2];
    }
    sb[t][0]=sx; sb[t][1]=sy; sb[t][2]=sz;
    __syncthreads();
    for (int off=128; off; off>>=1){
        if (t < off){ sb[t][0]+=sb[t+off][0]; sb[t][1]+=sb[t+off][1]; sb[t][2]+=sb[t+off][2]; }
        __syncthreads();
    }
    if (t < 3){
        float c = sb[0][t] / 16384.0f;
        center[b*3+t] = c;
        out[b*3+t] = c;      // output 0: center (32,3)
    }
}

// ===================== k_fps =====================
// Latency-minimized FPS. One block per batch. Key ideas vs v1:
//  - winner COORDS carried through the shuffle reduce (no dependent global
//    centroid load per iteration)
//  - (dist,idx) packed as sortable u64 (dist>=0 so raw float bits order;
//    ~idx gives lowest-index-wins on ties = JAX argmax semantics)
//  - double-buffered per-wave winner slots -> ONE barrier per iteration
//  - every thread redundantly scans the NW wave-winners (broadcast LDS reads)
// Per-thread dist math is bit-identical to v1 (same fpsdist, same centered
// coords), and (v,idx) order is strict, so selections are unchanged.
template<int N, int NPOINT, int NTH, int PPT, bool SUB>
__global__ __launch_bounds__(NTH) void k_fps(const float* __restrict__ src,
                                             const float* __restrict__ center,
                                             int* __restrict__ idx_out){
    static_assert(N == NTH*PPT, "bad fps cfg");
    constexpr int NW = NTH/64;
    int b = blockIdx.x, t = threadIdx.x;
    int wid = t>>6, lane = t&63;

    __shared__ unsigned int s_khi[2][NW], s_klo[2][NW];
    __shared__ float s_wx[2][NW], s_wy[2][NW], s_wz[2][NW];
    __shared__ float s_c0[3];

    float cx0=0.f, cy0=0.f, cz0=0.f;
    if constexpr (SUB){
        cx0 = center[b*3+0]; cy0 = center[b*3+1]; cz0 = center[b*3+2];
    }
    float px[PPT], py[PPT], pz[PPT], dist[PPT];
    #pragma unroll
    for (int i=0;i<PPT;i++){
        int p = t + i*NTH;
        const float* sp = src + ((size_t)b*N + p)*3;
        px[i]=sp[0]-cx0; py[i]=sp[1]-cy0; pz[i]=sp[2]-cz0;
        dist[i]=1e10f;
    }
    if (t==0){
        idx_out[b*NPOINT] = 0;
        s_c0[0]=px[0]; s_c0[1]=py[0]; s_c0[2]=pz[0];   // point 0 coords (t=0,i=0)
    }
    __syncthreads();
    float cx=s_c0[0], cy=s_c0[1], cz=s_c0[2];

    for (int it=1; it<NPOINT; ++it){
        int par = it & 1;
        // ---- update + in-thread argmax (carry coords) ----
        float bv = -1.0f; int bi = 0;
        float bx = 0.f, by = 0.f, bz = 0.f;
        #pragma unroll
        for (int i=0;i<PPT;i++){
            float d = fpsdist(px[i]-cx, py[i]-cy, pz[i]-cz);
            float nd = fminf(dist[i], d);
            dist[i] = nd;
            bool better = nd > bv;              // strict > : lowest slot wins in-thread
            bv = better ? nd : bv;
            bi = better ? (t + i*NTH) : bi;
            bx = better ? px[i] : bx;
            by = better ? py[i] : by;
            bz = better ? pz[i] : bz;
        }
        // ---- wave reduce: key = (bits(bv)<<32) | ~bi  (bv>=0 so bits order) ----
        unsigned long long key = ((unsigned long long)__float_as_uint(bv) << 32)
                               | (unsigned long long)(unsigned)(~(unsigned)bi);
        #pragma unroll
        for (int off=32; off>=1; off>>=1){
            unsigned long long ok = u64_shfl_down(key, off);
            float ox = __shfl_down(bx, off, 64);
            float oy = __shfl_down(by, off, 64);
            float oz = __shfl_down(bz, off, 64);
            bool better = ok > key;
            key = better ? ok : key;
            bx  = better ? ox : bx;
            by  = better ? oy : by;
            bz  = better ? oz : bz;
        }
        if (lane==0){
            s_khi[par][wid] = (unsigned)(key >> 32);
            s_klo[par][wid] = (unsigned)key;
            s_wx[par][wid]  = bx;
            s_wy[par][wid]  = by;
            s_wz[par][wid]  = bz;
        }
        __syncthreads();
        // ---- all threads scan NW wave-winners (broadcast reads) ----
        unsigned long long gk = ((unsigned long long)s_khi[par][0] << 32) | s_klo[par][0];
        int gw = 0;
        #pragma unroll
        for (int w2=1; w2<NW; ++w2){
            unsigned long long k2 = ((unsigned long long)s_khi[par][w2] << 32) | s_klo[par][w2];
            if (k2 > gk){ gk = k2; gw = w2; }
        }
        cx = s_wx[par][gw]; cy = s_wy[par][gw]; cz = s_wz[par][gw];
        if (t==0) idx_out[b*NPOINT + it] = (int)(~(unsigned)(gk & 0xFFFFFFFFull));
        // no second barrier: next iteration writes parity par^1
    }
}

// ===================== k_gather1 =====================
__global__ __launch_bounds__(64) void k_gather1(const float* __restrict__ xyz,
                                                const float* __restrict__ f,
                                                const float* __restrict__ center,
                                                const float* __restrict__ conv1_w,
                                                const float* __restrict__ bn1_g,
                                                const float* __restrict__ bn1_b,
                                                const int* __restrict__ fps_idx,
                                                float* __restrict__ new_xyz,
                                                float* __restrict__ np_feat){
    int q = blockIdx.x; int b = q>>7, s = q&127;
    int o = threadIdx.x;
    int idx = fps_idx[b*128+s];
    const float* xp = xyz + ((size_t)b*16384 + idx)*3;
    const float* fp = f   + ((size_t)b*16384 + idx)*3;
    float p0 = xp[0]-center[b*3+0], p1 = xp[1]-center[b*3+1], p2 = xp[2]-center[b*3+2];
    float p3 = fp[0], p4 = fp[1], p5 = fp[2];
    const float* w = conv1_w + o*6;
    float v = conv_feat6(p0,p1,p2,p3,p4,p5, w[0],w[1],w[2],w[3],w[4],w[5],
                         bnscale(bn1_g[o]), bn1_b[o]);
    np_feat[((size_t)b*128 + s)*64 + o] = v;
    if (o < 3){
        float pc = (o==0)?p0:((o==1)?p1:p2);
        new_xyz[((size_t)b*128 + s)*3 + o] = pc;
    }
}

// ===================== k_knn1 =====================
__global__ __launch_bounds__(256) void k_knn1(const float* __restrict__ xyz,
                                              const float* __restrict__ center,
                                              const float* __restrict__ new_xyz,
                                              int* __restrict__ knn_idx){
    int q = blockIdx.x; int b = q>>7;
    int t = threadIdx.x;
    __shared__ unsigned long long scmin[256];

    float cx = center[b*3+0], cy = center[b*3+1], cz = center[b*3+2];
    float qx = new_xyz[(size_t)q*3+0], qy = new_xyz[(size_t)q*3+1], qz = new_xyz[(size_t)q*3+2];
    float qs = sumsq3(qx,qy,qz);
    const float* xb = xyz + (size_t)b*16384*3;

    // phase 1: chunk t = points {t + 256*i}
    unsigned long long m = 0xFFFFFFFFFFFFFFFFull;
    for (int i=0;i<64;i++){
        int n = t + (i<<8);
        const float* p = xb + (size_t)n*3;
        float px = p[0]-cx, py = p[1]-cy, pz = p[2]-cz;
        float d = sqdist3(qx,qy,qz,qs,px,py,pz);
        m = u64min(m, packdi(d, (unsigned)n));
    }
    scmin[t] = m;
    __syncthreads();
    if (t >= 64) return;        // wave 0 does the rounds

    for (int r=0; r<32; ++r){
        unsigned long long mm = u64min(u64min(scmin[t], scmin[t+64]),
                                       u64min(scmin[t+128], scmin[t+192]));
        #pragma unroll
        for (int off=32; off>=1; off>>=1) mm = u64min(mm, u64_shfl_down(mm, off));
        unsigned long long win = u64_bcast0(mm);
        unsigned int widx = (unsigned int)(win & 0xFFFFFFFFull);
        if (t==0) knn_idx[(size_t)q*32 + r] = (int)widx;
        int c = (int)(widx & 255u);
        // rescan chunk c excluding everything already selected (packed <= win)
        int n = c + (t<<8);
        const float* p = xb + (size_t)n*3;
        float px = p[0]-cx, py = p[1]-cy, pz = p[2]-cz;
        float d = sqdist3(qx,qy,qz,qs,px,py,pz);
        unsigned long long pk = packdi(d, (unsigned)n);
        if (pk <= win) pk = 0xFFFFFFFFFFFFFFFFull;
        #pragma unroll
        for (int off=32; off>=1; off>>=1) pk = u64min(pk, u64_shfl_down(pk, off));
        if (t==0) scmin[c] = pk;
    }
}

// ===================== k_gather2 =====================
__global__ __launch_bounds__(64) void k_gather2(const float* __restrict__ new_xyz1,
                                                const float* __restrict__ feat,
                                                const int* __restrict__ fps2,
                                                float* __restrict__ new_xyz2,
                                                float* __restrict__ np2){
    int q = blockIdx.x; int b = q>>5, s = q&31;
    int o = threadIdx.x;
    int idx = fps2[b*32+s];
    np2[((size_t)b*32 + s)*64 + o] = feat[((size_t)b*128 + idx)*64 + o];
    if (o < 3) new_xyz2[((size_t)b*32 + s)*3 + o] = new_xyz1[((size_t)b*128 + idx)*3 + o];
}

// ===================== k_knn2 =====================
__global__ __launch_bounds__(256) void k_knn2(const float* __restrict__ pts,   // new_xyz1 (b,128,3)
                                              const float* __restrict__ qpts,  // new_xyz2 (b,32,3)
                                              int* __restrict__ knn_idx){
    int t = threadIdx.x;
    int wid = t>>6, lane = t&63;
    int q = blockIdx.x*4 + wid;      // 0..1023
    int b = q>>5;
    float qx = qpts[(size_t)q*3+0], qy = qpts[(size_t)q*3+1], qz = qpts[(size_t)q*3+2];
    float qs = sumsq3(qx,qy,qz);
    const float* pb = pts + (size_t)b*128*3;

    unsigned long long p0, p1;
    {
        int n = lane;
        float px=pb[n*3+0], py=pb[n*3+1], pz=pb[n*3+2];
        p0 = packdi(sqdist3(qx,qy,qz,qs,px,py,pz), (unsigned)n);
        n = lane + 64;
        px=pb[n*3+0]; py=pb[n*3+1]; pz=pb[n*3+2];
        p1 = packdi(sqdist3(qx,qy,qz,qs,px,py,pz), (unsigned)n);
    }
    for (int r=0; r<16; ++r){
        unsigned long long mm = u64min(p0, p1);
        #pragma unroll
        for (int off=32; off>=1; off>>=1) mm = u64min(mm, u64_shfl_down(mm, off));
        unsigned long long win = u64_bcast0(mm);
        if (lane==0) knn_idx[(size_t)q*16 + r] = (int)(win & 0xFFFFFFFFull);
        if (p0 == win) p0 = 0xFFFFFFFFFFFFFFFFull;
        if (p1 == win) p1 = 0xFFFFFFFFFFFFFFFFull;
    }
}

// ===================== k_group_local =====================
// grouped MLP + maxpool. One wave per query, lane = output channel.
// v2: wt padded to stride 65 (bank-conflict-free staging writes AND compute
// reads), neighbor gathers prefetched in parallel (indices via __shfl).
template<int K, int NQ, int NSRC, bool RECOMP>
__global__ __launch_bounds__(256) void k_group_local(
    const float* __restrict__ xyz, const float* __restrict__ f, const float* __restrict__ center,
    const float* __restrict__ conv1_w, const float* __restrict__ bn1_g, const float* __restrict__ bn1_b,
    const float* __restrict__ src_feat,
    const int* __restrict__ knn_idx, const float* __restrict__ np_feat,
    const float* __restrict__ w, const float* __restrict__ g, const float* __restrict__ bb,
    float* __restrict__ out)
{
    __shared__ float wt[128*65];          // wt[d*65+o] = w[o*128+d]; stride 65 -> conflict-free
    __shared__ float s_sc[64], s_bs[64];
    __shared__ float cwT[6*64];           // conv weights transposed [j][o]
    __shared__ float s_csc[64], s_cbs[64];
    __shared__ float np_l[4][64];
    __shared__ float gd[4][64];
    __shared__ float s_pts[4][K > 1 ? K : 1][6];     // RECOMP raw points
    __shared__ float gdall[RECOMP ? 1 : 4][RECOMP ? 1 : K][64];  // !RECOMP prefetched feats

    int t = threadIdx.x;
    for (int e=t; e<8192; e+=256){ int o = e>>7, d = e&127; wt[d*65 + o] = w[e]; }
    if (t < 64){ s_sc[t] = bnscale(g[t]); s_bs[t] = bb[t]; }
    if constexpr (RECOMP){
        for (int e=t; e<384; e+=256){ int o = e/6, j = e%6; cwT[j*64 + o] = conv1_w[e]; }
        if (t < 64){ s_csc[t] = bnscale(bn1_g[t]); s_cbs[t] = bn1_b[t]; }
    }
    __syncthreads();

    int wid = t>>6, lane = t&63;
    int q = blockIdx.x*4 + wid;
    int b = q / NQ, s = q % NQ;

    float np_o = np_feat[((size_t)b*NQ + s)*64 + lane];
    np_l[wid][lane] = np_o;

    // rep-term (constant over k)
    float C = 0.f;
    #pragma unroll
    for (int d=0; d<64; d++) C = fmaf(np_l[wid][d], wt[(64+d)*65 + lane], C);

    const int* kix = knn_idx + ((size_t)b*NQ + s)*K;
    int myi = kix[lane < K ? lane : 0];

    if constexpr (RECOMP){
        // lanes 0..K-1 gather xyz, lanes 32..32+K-1 gather f (parallel, wave-local)
        float cx = center[b*3+0], cy = center[b*3+1], cz = center[b*3+2];
        if (lane < K){
            const float* xp = xyz + ((size_t)b*16384 + myi)*3;
            s_pts[wid][lane][0] = xp[0]-cx;
            s_pts[wid][lane][1] = xp[1]-cy;
            s_pts[wid][lane][2] = xp[2]-cz;
            const float* fp = f + ((size_t)b*16384 + myi)*3;
            s_pts[wid][lane][3] = fp[0];
            s_pts[wid][lane][4] = fp[1];
            s_pts[wid][lane][5] = fp[2];
        }
    } else {
        // prefetch all K neighbor features (independent coalesced loads)
        #pragma unroll
        for (int k=0; k<K; ++k){
            int ik = __shfl(myi, k, 64);
            gdall[wid][k][lane] = src_feat[((size_t)b*NSRC + ik)*64 + lane] - np_o;
        }
    }

    float acc = -1e30f;
    #pragma unroll 4
    for (int k=0; k<K; ++k){
        float y = C;
        if constexpr (RECOMP){
            float gv = conv_feat6(s_pts[wid][k][0], s_pts[wid][k][1], s_pts[wid][k][2],
                                  s_pts[wid][k][3], s_pts[wid][k][4], s_pts[wid][k][5],
                                  cwT[0*64+lane], cwT[1*64+lane], cwT[2*64+lane],
                                  cwT[3*64+lane], cwT[4*64+lane], cwT[5*64+lane],
                                  s_csc[lane], s_cbs[lane]);
            gd[wid][lane] = gv - np_o;        // wave-ordered LDS: write then read below
            #pragma unroll
            for (int d=0; d<64; d++) y = fmaf(gd[wid][d], wt[d*65 + lane], y);
        } else {
            #pragma unroll
            for (int d=0; d<64; d++) y = fmaf(gdall[wid][k][d], wt[d*65 + lane], y);
        }
        float v = fmaxf(fmaf(y, s_sc[lane], s_bs[lane]), 0.0f);
        acc = fmaxf(acc, v);
    }
    out[((size_t)b*NQ + s)*64 + lane] = acc;
}

// ===================== k_tail =====================
__device__ void sa_block(const float* X, float* Xout,
                         float* Q, float* E, float* XV, float* XR, float* CS,
                         const float* qk_w, const float* v_w, const float* v_b,
                         const float* t_w, const float* t_b,
                         const float* g, const float* bb, int t)
{
    for (int e=t; e<512; e+=256){
        int n = e>>4, o = e&15;
        float y = 0.f;
        for (int c=0;c<64;c++) y = fmaf(qk_w[o*64+c], X[c*32+n], y);
        Q[n*16+o] = y;
    }
    for (int e=t; e<2048; e+=256){
        int o = e>>5, n = e&31;
        float y = v_b[o];
        for (int c=0;c<64;c++) y = fmaf(v_w[o*64+c], X[c*32+n], y);
        XV[o*32+n] = y;
    }
    __syncthreads();
    for (int e=t; e<1024; e+=256){
        int n = e>>5, m = e&31;
        float y = 0.f;
        for (int d=0;d<16;d++) y = fmaf(Q[n*16+d], Q[m*16+d], y);
        E[e] = y;
    }
    __syncthreads();
    if (t < 32){
        float mx = -1e30f;
        for (int m=0;m<32;m++) mx = fmaxf(mx, E[t*32+m]);
        float sum = 0.f;
        for (int m=0;m<32;m++){ float v = expf(E[t*32+m]-mx); E[t*32+m]=v; sum += v; }
        for (int m=0;m<32;m++) E[t*32+m] = E[t*32+m] / sum;
    }
    __syncthreads();
    if (t < 32){
        float cs = 0.f;
        for (int n=0;n<32;n++) cs += E[n*32+t];
        CS[t] = 1e-9f + cs;
    }
    __syncthreads();
    for (int e=t; e<1024; e+=256) E[e] = E[e] / CS[e&31];
    __syncthreads();
    for (int e=t; e<2048; e+=256){
        int c = e>>5, m = e&31;
        float y = 0.f;
        for (int n=0;n<32;n++) y = fmaf(XV[c*32+n], E[n*32+m], y);
        XR[c*32+m] = y;
    }
    __syncthreads();
    for (int e=t; e<2048; e+=256){
        int o = e>>5, n = e&31;
        float y = 0.f;
        for (int c=0;c<64;c++) y = fmaf(t_w[o*64+c], X[c*32+n]-XR[c*32+n], y);
        y += t_b[o];
        y = fmaxf(fmaf(y, bnscale(g[o]), bb[o]), 0.0f);
        Xout[e] = X[e] + y;
    }
    __syncthreads();
}

__global__ __launch_bounds__(256) void k_tail(
    const float* __restrict__ f1buf,   // (b,32,64)
    const float* st_c1_w, const float* st_bn1_g, const float* st_bn1_b,
    const float* st_c2_w, const float* st_bn2_g, const float* st_bn2_b,
    const float* sa1_qk, const float* sa1_v, const float* sa1_vb,
    const float* sa1_t, const float* sa1_tb, const float* sa1_g, const float* sa1_b,
    const float* sa2_qk, const float* sa2_v, const float* sa2_vb,
    const float* sa2_t, const float* sa2_tb, const float* sa2_g, const float* sa2_b,
    const float* fuse_w, const float* fuse_g, const float* fuse_b,
    const float* lin1_w, const float* bn6_g, const float* bn6_b,
    const float* lin2_w, const float* lin2_b,
    float* __restrict__ out)
{
    __shared__ float sm[14848];
    float* F1 = sm;            // 2048  [c][n]
    float* XA = sm + 2048;     // 2048
    float* XB = sm + 4096;     // 2048
    float* Q  = sm + 6144;     // 512
    float* E  = sm + 6656;     // 1024
    float* XV = sm + 7680;     // 2048
    float* XR = sm + 9728;     // 2048
    float* CS = sm + 11776;    // 32
    float* FO = sm + 6144;     // 8192 (reuses SA scratch after SA done)
    float* PO = sm + 14336;    // 256
    float* P2 = sm + 14592;    // 256

    int b = blockIdx.x, t = threadIdx.x;

    for (int e=t; e<2048; e+=256){ int n = e>>6, c = e&63; F1[c*32+n] = f1buf[((size_t)b*32+n)*64 + c]; }
    __syncthreads();
    for (int e=t; e<2048; e+=256){
        int o = e>>5, n = e&31;
        float y = 0.f;
        for (int c=0;c<64;c++) y = fmaf(st_c1_w[o*64+c], F1[c*32+n], y);
        XA[e] = fmaxf(fmaf(y, bnscale(st_bn1_g[o]), st_bn1_b[o]), 0.0f);
    }
    __syncthreads();
    for (int e=t; e<2048; e+=256){
        int o = e>>5, n = e&31;
        float y = 0.f;
        for (int c=0;c<64;c++) y = fmaf(st_c2_w[o*64+c], XA[c*32+n], y);
        XB[e] = fmaxf(fmaf(y, bnscale(st_bn2_g[o]), st_bn2_b[o]), 0.0f);
    }
    __syncthreads();
    sa_block(XB, XA, Q,E,XV,XR,CS, sa1_qk, sa1_v, sa1_vb, sa1_t, sa1_tb, sa1_g, sa1_b, t); // x1 -> XA
    sa_block(XA, XB, Q,E,XV,XR,CS, sa2_qk, sa2_v, sa2_vb, sa2_t, sa2_tb, sa2_g, sa2_b, t); // x2 -> XB
    for (int e=t; e<8192; e+=256){
        int o = e>>5, n = e&31;
        const float* wr = fuse_w + o*192;
        float y = 0.f;
        for (int c=0;c<64;c++) y = fmaf(wr[c],      XA[c*32+n], y);
        for (int c=0;c<64;c++) y = fmaf(wr[64+c],   XB[c*32+n], y);
        for (int c=0;c<64;c++) y = fmaf(wr[128+c],  F1[c*32+n], y);
        float v = fmaf(y, bnscale(fuse_g[o]), fuse_b[o]);
        FO[e] = (v > 0.0f) ? v : 0.2f*v;
    }
    __syncthreads();
    {
        float mx = -1e30f;
        for (int n=0;n<32;n++) mx = fmaxf(mx, FO[t*32+n]);
        PO[t] = mx;
    }
    __syncthreads();
    {
        const float* wr = lin1_w + t*256;
        float y = 0.f;
        for (int c=0;c<256;c++) y = fmaf(wr[c], PO[c], y);
        P2[t] = fmaxf(fmaf(y, bnscale(bn6_g[t]), bn6_b[t]), 0.0f);
    }
    __syncthreads();
    {
        const float* wr = lin2_w + t*256;
        float y = 0.f;
        for (int c=0;c<256;c++) y = fmaf(wr[c], P2[c], y);
        out[96 + b*256 + t] = y + lin2_b[t];
    }
}

// ===================== launch =====================
extern "C" void kernel_launch(void* const* d_in, const int* in_sizes, int n_in,
                              void* d_out, int out_size, void* d_ws, size_t ws_size,
                              hipStream_t stream)
{
    const float* xyz      = (const float*)d_in[0];
    const float* f        = (const float*)d_in[1];
    const float* conv1_w  = (const float*)d_in[2];
    const float* bn1_g    = (const float*)d_in[3];
    const float* bn1_b    = (const float*)d_in[4];
    const float* l0_w     = (const float*)d_in[5];
    const float* l0_g     = (const float*)d_in[6];
    const float* l0_b     = (const float*)d_in[7];
    const float* l1_w     = (const float*)d_in[8];
    const float* l1_g     = (const float*)d_in[9];
    const float* l1_b     = (const float*)d_in[10];
    const float* st_c1_w  = (const float*)d_in[11];
    const float* st_bn1_g = (const float*)d_in[12];
    const float* st_bn1_b = (const float*)d_in[13];
    const float* st_c2_w  = (const float*)d_in[14];
    const float* st_bn2_g = (const float*)d_in[15];
    const float* st_bn2_b = (const float*)d_in[16];
    const float* sa1_qk   = (const float*)d_in[17];
    const float* sa1_v    = (const float*)d_in[18];
    const float* sa1_vb   = (const float*)d_in[19];
    const float* sa1_t    = (const float*)d_in[20];
    const float* sa1_tb   = (const float*)d_in[21];
    const float* sa1_g    = (const float*)d_in[22];
    const float* sa1_b    = (const float*)d_in[23];
    const float* sa2_qk   = (const float*)d_in[24];
    const float* sa2_v    = (const float*)d_in[25];
    const float* sa2_vb   = (const float*)d_in[26];
    const float* sa2_t    = (const float*)d_in[27];
    const float* sa2_tb   = (const float*)d_in[28];
    const float* sa2_g    = (const float*)d_in[29];
    const float* sa2_b    = (const float*)d_in[30];
    const float* fuse_w   = (const float*)d_in[31];
    const float* fuse_g   = (const float*)d_in[32];
    const float* fuse_b   = (const float*)d_in[33];
    const float* lin1_w   = (const float*)d_in[34];
    const float* bn6_g    = (const float*)d_in[35];
    const float* bn6_b    = (const float*)d_in[36];
    const float* lin2_w   = (const float*)d_in[37];
    const float* lin2_b   = (const float*)d_in[38];
    float* out = (float*)d_out;

    float* ws = (float*)d_ws;
    float* center   = ws + 0;        // 96
    float* new_xyz1 = ws + 96;       // 12288
    float* np1      = ws + 12384;    // 262144
    float* feat     = ws + 274528;   // 262144
    float* new_xyz2 = ws + 536672;   // 3072
    float* np2      = ws + 539744;   // 65536
    float* f1       = ws + 605280;   // 65536
    int*   fps1     = (int*)(ws + 670816);  // 4096
    int*   knn1     = (int*)(ws + 674912);  // 131072
    int*   fps2     = (int*)(ws + 805984);  // 1024
    int*   knn2     = (int*)(ws + 807008);  // 16384

    k_center<<<32, 256, 0, stream>>>(xyz, center, out);
    k_fps<16384,128,512,32,true><<<32, 512, 0, stream>>>(xyz, center, fps1);
    k_gather1<<<4096, 64, 0, stream>>>(xyz, f, center, conv1_w, bn1_g, bn1_b, fps1, new_xyz1, np1);
    k_knn1<<<4096, 256, 0, stream>>>(xyz, center, new_xyz1, knn1);
    k_group_local<32,128,1,true><<<1024, 256, 0, stream>>>(
        xyz, f, center, conv1_w, bn1_g, bn1_b, nullptr, knn1, np1, l0_w, l0_g, l0_b, feat);
    k_fps<128,32,128,1,false><<<32, 128, 0, stream>>>(new_xyz1, nullptr, fps2);
    k_gather2<<<1024, 64, 0, stream>>>(new_xyz1, feat, fps2, new_xyz2, np2);
    k_knn2<<<256, 256, 0, stream>>>(new_xyz1, new_xyz2, knn2);
    k_group_local<16,32,128,false><<<256, 256, 0, stream>>>(
        nullptr, nullptr, nullptr, nullptr, nullptr, nullptr, feat, knn2, np2, l1_w, l1_g, l1_b, f1);
    k_tail<<<32, 256, 0, stream>>>(f1,
        st_c1_w, st_bn1_g, st_bn1_b, st_c2_w, st_bn2_g, st_bn2_b,
        sa1_qk, sa1_v, sa1_vb, sa1_t, sa1_tb, sa1_g, sa1_b,
        sa2_qk, sa2_v, sa2_vb, sa2_t, sa2_tb, sa2_g, sa2_b,
        fuse_w, fuse_g, fuse_b, lin1_w, bn6_g, bn6_b, lin2_w, lin2_b, out);
}

// Round 4
// 651.875 us; speedup vs baseline: 1.3538x; 1.1719x over previous
//
#include <hip/hip_runtime.h>

// ===================== helpers =====================

__device__ __forceinline__ float bnscale(float g){ return g / sqrtf(1.0f + 1e-5f); }

__device__ __forceinline__ float conv_feat6(float p0,float p1,float p2,float p3,float p4,float p5,
                                            float w0,float w1,float w2,float w3,float w4,float w5,
                                            float sc,float bs){
    float y = p0*w0;
    y = fmaf(p1,w1,y); y = fmaf(p2,w2,y); y = fmaf(p3,w3,y);
    y = fmaf(p4,w4,y); y = fmaf(p5,w5,y);
    return fmaxf(fmaf(y,sc,bs), 0.0f);
}

// FPS distance: matches jnp.sum((p-c)**2, -1) left-to-right, NO contraction
__device__ __forceinline__ float fpsdist(float dx,float dy,float dz){
    #pragma clang fp contract(off)
    return (dx*dx + dy*dy) + dz*dz;
}

// square_distance(): d = (-2*dot + |q|^2) + |p|^2, left-to-right, NO contraction.
__device__ __forceinline__ float sumsq3(float x,float y,float z){
    #pragma clang fp contract(off)
    return (x*x + y*y) + z*z;
}
__device__ __forceinline__ float sqdist3(float qx,float qy,float qz,float qs,
                                         float px,float py,float pz){
    #pragma clang fp contract(off)
    {
        float dot = (qx*px + qy*py) + qz*pz;
        float pn  = (px*px + py*py) + pz*pz;
        return (-2.0f*dot + qs) + pn;
    }
}

// pack (dist,idx) into sortable u64: ascending u64 == ascending (dist, idx) lexicographic
__device__ __forceinline__ unsigned long long packdi(float d, unsigned int idx){
    unsigned int u = __float_as_uint(d);
    unsigned int msk = (unsigned int)((int)u >> 31);
    u ^= (msk | 0x80000000u);
    return ((unsigned long long)u << 32) | (unsigned long long)idx;
}

__device__ __forceinline__ unsigned long long u64min(unsigned long long a, unsigned long long b){
    return a < b ? a : b;
}

__device__ __forceinline__ unsigned long long u64_shfl_down(unsigned long long v, int off){
    unsigned int lo = (unsigned int)v, hi = (unsigned int)(v >> 32);
    lo = __shfl_down(lo, off, 64);
    hi = __shfl_down(hi, off, 64);
    return ((unsigned long long)hi << 32) | (unsigned long long)lo;
}

__device__ __forceinline__ unsigned long long u64_bcast0(unsigned long long v){
    unsigned int lo = (unsigned int)v, hi = (unsigned int)(v >> 32);
    lo = __shfl(lo, 0, 64);
    hi = __shfl(hi, 0, 64);
    return ((unsigned long long)hi << 32) | (unsigned long long)lo;
}

// ===================== k_fps1 =====================
// Merged center-compute + FPS(16384->128). One block (512 thr) per batch.
// v3: launch_bounds(512,2) -> 256-VGPR budget so px/py/pz/dist[32] stay
// resident; key-only wave reduce; winner coords re-fetched via uniform
// broadcast L2 load (bit-identical expression to the register value).
__global__ __launch_bounds__(512, 2) void k_fps1(const float* __restrict__ xyz,
                                                 float* __restrict__ center,
                                                 float* __restrict__ out,
                                                 int* __restrict__ idx_out){
    constexpr int NTH = 512, PPT = 32, N = 16384, NPOINT = 128, NW = 8;
    int b = blockIdx.x, t = threadIdx.x;
    int wid = t>>6, lane = t&63;

    __shared__ float s_red[NW][3];
    __shared__ unsigned int s_khi[2][NW], s_klo[2][NW];

    const float* xb = xyz + (size_t)b*N*3;
    float px[PPT], py[PPT], pz[PPT], dist[PPT];
    #pragma unroll
    for (int i=0;i<PPT;i++){
        const float* sp = xb + (size_t)(t + i*NTH)*3;
        px[i]=sp[0]; py[i]=sp[1]; pz[i]=sp[2];
        dist[i]=1e10f;
    }
    // ---- block mean (center) ----
    float sx=0.f, sy=0.f, sz=0.f;
    #pragma unroll
    for (int i=0;i<PPT;i++){ sx+=px[i]; sy+=py[i]; sz+=pz[i]; }
    #pragma unroll
    for (int off=32; off>=1; off>>=1){
        sx += __shfl_down(sx, off, 64);
        sy += __shfl_down(sy, off, 64);
        sz += __shfl_down(sz, off, 64);
    }
    if (lane==0){ s_red[wid][0]=sx; s_red[wid][1]=sy; s_red[wid][2]=sz; }
    __syncthreads();
    float cx0=0.f, cy0=0.f, cz0=0.f;
    #pragma unroll
    for (int w2=0; w2<NW; ++w2){ cx0+=s_red[w2][0]; cy0+=s_red[w2][1]; cz0+=s_red[w2][2]; }
    cx0 *= (1.0f/16384.0f); cy0 *= (1.0f/16384.0f); cz0 *= (1.0f/16384.0f);
    if (t < 3){
        float c = (t==0)?cx0:((t==1)?cy0:cz0);
        center[b*3+t] = c;
        out[b*3+t] = c;           // output 0: center (32,3)
    }
    #pragma unroll
    for (int i=0;i<PPT;i++){ px[i]-=cx0; py[i]-=cy0; pz[i]-=cz0; }
    if (t==0) idx_out[b*NPOINT] = 0;

    // initial centroid = centered point 0 (uniform broadcast load)
    float cx = xb[0]-cx0, cy = xb[1]-cy0, cz = xb[2]-cz0;

    for (int it=1; it<NPOINT; ++it){
        int par = it & 1;
        // ---- dist update + in-thread argmax (index only) ----
        float bv = -1.0f; int bi = 0;
        #pragma unroll
        for (int i=0;i<PPT;i++){
            float d = fpsdist(px[i]-cx, py[i]-cy, pz[i]-cz);
            float nd = fminf(dist[i], d);
            dist[i] = nd;
            bool better = nd > bv;          // strict > : lowest slot wins in-thread
            bv = better ? nd : bv;
            bi = better ? (t + i*NTH) : bi;
        }
        // ---- key-only wave reduce (bv>=0 so raw bits order; ~bi -> lowest idx wins) ----
        unsigned long long key = ((unsigned long long)__float_as_uint(bv) << 32)
                               | (unsigned long long)(unsigned)(~(unsigned)bi);
        #pragma unroll
        for (int off=32; off>=1; off>>=1){
            unsigned long long ok = u64_shfl_down(key, off);
            key = ok > key ? ok : key;
        }
        if (lane==0){ s_khi[par][wid]=(unsigned)(key>>32); s_klo[par][wid]=(unsigned)key; }
        __syncthreads();
        // ---- all threads scan NW wave winners ----
        unsigned long long gk = ((unsigned long long)s_khi[par][0] << 32) | s_klo[par][0];
        #pragma unroll
        for (int w2=1; w2<NW; ++w2){
            unsigned long long k2 = ((unsigned long long)s_khi[par][w2] << 32) | s_klo[par][w2];
            if (k2 > gk) gk = k2;
        }
        int gi = (int)(~(unsigned)(gk & 0xFFFFFFFFull));
        gi = __builtin_amdgcn_readfirstlane(gi);
        if (t==0) idx_out[b*NPOINT + it] = gi;
        // winner coords: uniform broadcast load, bit-identical to reg value
        const float* wp = xb + (size_t)gi*3;
        cx = wp[0]-cx0; cy = wp[1]-cy0; cz = wp[2]-cz0;
        // no second barrier: next iteration uses parity par^1
    }
}

// ===================== k_fps2 =====================
// FPS(128->32) on centered new_xyz1. ONE wave per batch: no LDS, no barriers.
__global__ __launch_bounds__(64) void k_fps2(const float* __restrict__ pts,
                                             int* __restrict__ idx_out){
    int b = blockIdx.x, lane = threadIdx.x;
    const float* pb = pts + (size_t)b*128*3;
    float px[2],py[2],pz[2],dist[2];
    #pragma unroll
    for (int i=0;i<2;i++){
        const float* sp = pb + (size_t)(lane + i*64)*3;
        px[i]=sp[0]; py[i]=sp[1]; pz[i]=sp[2];
        dist[i]=1e10f;
    }
    if (lane==0) idx_out[b*32] = 0;
    float cx=pb[0], cy=pb[1], cz=pb[2];

    for (int it=1; it<32; ++it){
        float bv=-1.0f; int bi=0;
        float bx=0.f, by=0.f, bz=0.f;
        #pragma unroll
        for (int i=0;i<2;i++){
            float d = fpsdist(px[i]-cx, py[i]-cy, pz[i]-cz);
            float nd = fminf(dist[i], d);
            dist[i]=nd;
            bool better = nd > bv;
            bv = better ? nd : bv;
            bi = better ? (lane + i*64) : bi;
            bx = better ? px[i] : bx;
            by = better ? py[i] : by;
            bz = better ? pz[i] : bz;
        }
        unsigned long long key = ((unsigned long long)__float_as_uint(bv) << 32)
                               | (unsigned long long)(unsigned)(~(unsigned)bi);
        #pragma unroll
        for (int off=32; off>=1; off>>=1){
            unsigned long long ok = u64_shfl_down(key, off);
            float ox = __shfl_down(bx, off, 64);
            float oy = __shfl_down(by, off, 64);
            float oz = __shfl_down(bz, off, 64);
            bool better = ok > key;
            key = better ? ok : key;
            bx = better ? ox : bx;
            by = better ? oy : by;
            bz = better ? oz : bz;
        }
        key = u64_bcast0(key);
        cx = __shfl(bx, 0, 64); cy = __shfl(by, 0, 64); cz = __shfl(bz, 0, 64);
        if (lane==0) idx_out[b*32 + it] = (int)(~(unsigned)(key & 0xFFFFFFFFull));
    }
}

// ===================== k_gather1 =====================
__global__ __launch_bounds__(64) void k_gather1(const float* __restrict__ xyz,
                                                const float* __restrict__ f,
                                                const float* __restrict__ center,
                                                const float* __restrict__ conv1_w,
                                                const float* __restrict__ bn1_g,
                                                const float* __restrict__ bn1_b,
                                                const int* __restrict__ fps_idx,
                                                float* __restrict__ new_xyz,
                                                float* __restrict__ np_feat){
    int q = blockIdx.x; int b = q>>7, s = q&127;
    int o = threadIdx.x;
    int idx = fps_idx[b*128+s];
    const float* xp = xyz + ((size_t)b*16384 + idx)*3;
    const float* fp = f   + ((size_t)b*16384 + idx)*3;
    float p0 = xp[0]-center[b*3+0], p1 = xp[1]-center[b*3+1], p2 = xp[2]-center[b*3+2];
    float p3 = fp[0], p4 = fp[1], p5 = fp[2];
    const float* w = conv1_w + o*6;
    float v = conv_feat6(p0,p1,p2,p3,p4,p5, w[0],w[1],w[2],w[3],w[4],w[5],
                         bnscale(bn1_g[o]), bn1_b[o]);
    np_feat[((size_t)b*128 + s)*64 + o] = v;
    if (o < 3){
        float pc = (o==0)?p0:((o==1)?p1:p2);
        new_xyz[((size_t)b*128 + s)*3 + o] = pc;
    }
}

// ===================== k_knn1 =====================
__global__ __launch_bounds__(256) void k_knn1(const float* __restrict__ xyz,
                                              const float* __restrict__ center,
                                              const float* __restrict__ new_xyz,
                                              int* __restrict__ knn_idx){
    int q = blockIdx.x; int b = q>>7;
    int t = threadIdx.x;
    __shared__ unsigned long long scmin[256];

    float cx = center[b*3+0], cy = center[b*3+1], cz = center[b*3+2];
    float qx = new_xyz[(size_t)q*3+0], qy = new_xyz[(size_t)q*3+1], qz = new_xyz[(size_t)q*3+2];
    float qs = sumsq3(qx,qy,qz);
    const float* xb = xyz + (size_t)b*16384*3;

    unsigned long long m = 0xFFFFFFFFFFFFFFFFull;
    for (int i=0;i<64;i++){
        int n = t + (i<<8);
        const float* p = xb + (size_t)n*3;
        float px = p[0]-cx, py = p[1]-cy, pz = p[2]-cz;
        float d = sqdist3(qx,qy,qz,qs,px,py,pz);
        m = u64min(m, packdi(d, (unsigned)n));
    }
    scmin[t] = m;
    __syncthreads();
    if (t >= 64) return;        // wave 0 does the rounds

    for (int r=0; r<32; ++r){
        unsigned long long mm = u64min(u64min(scmin[t], scmin[t+64]),
                                       u64min(scmin[t+128], scmin[t+192]));
        #pragma unroll
        for (int off=32; off>=1; off>>=1) mm = u64min(mm, u64_shfl_down(mm, off));
        unsigned long long win = u64_bcast0(mm);
        unsigned int widx = (unsigned int)(win & 0xFFFFFFFFull);
        if (t==0) knn_idx[(size_t)q*32 + r] = (int)widx;
        int c = (int)(widx & 255u);
        int n = c + (t<<8);
        const float* p = xb + (size_t)n*3;
        float px = p[0]-cx, py = p[1]-cy, pz = p[2]-cz;
        float d = sqdist3(qx,qy,qz,qs,px,py,pz);
        unsigned long long pk = packdi(d, (unsigned)n);
        if (pk <= win) pk = 0xFFFFFFFFFFFFFFFFull;
        #pragma unroll
        for (int off=32; off>=1; off>>=1) pk = u64min(pk, u64_shfl_down(pk, off));
        if (t==0) scmin[c] = pk;
    }
}

// ===================== k_gather2 =====================
__global__ __launch_bounds__(64) void k_gather2(const float* __restrict__ new_xyz1,
                                                const float* __restrict__ feat,
                                                const int* __restrict__ fps2,
                                                float* __restrict__ new_xyz2,
                                                float* __restrict__ np2){
    int q = blockIdx.x; int b = q>>5, s = q&31;
    int o = threadIdx.x;
    int idx = fps2[b*32+s];
    np2[((size_t)b*32 + s)*64 + o] = feat[((size_t)b*128 + idx)*64 + o];
    if (o < 3) new_xyz2[((size_t)b*32 + s)*3 + o] = new_xyz1[((size_t)b*128 + idx)*3 + o];
}

// ===================== k_knn2 =====================
__global__ __launch_bounds__(256) void k_knn2(const float* __restrict__ pts,
                                              const float* __restrict__ qpts,
                                              int* __restrict__ knn_idx){
    int t = threadIdx.x;
    int wid = t>>6, lane = t&63;
    int q = blockIdx.x*4 + wid;
    int b = q>>5;
    float qx = qpts[(size_t)q*3+0], qy = qpts[(size_t)q*3+1], qz = qpts[(size_t)q*3+2];
    float qs = sumsq3(qx,qy,qz);
    const float* pb = pts + (size_t)b*128*3;

    unsigned long long p0, p1;
    {
        int n = lane;
        float px=pb[n*3+0], py=pb[n*3+1], pz=pb[n*3+2];
        p0 = packdi(sqdist3(qx,qy,qz,qs,px,py,pz), (unsigned)n);
        n = lane + 64;
        px=pb[n*3+0]; py=pb[n*3+1]; pz=pb[n*3+2];
        p1 = packdi(sqdist3(qx,qy,qz,qs,px,py,pz), (unsigned)n);
    }
    for (int r=0; r<16; ++r){
        unsigned long long mm = u64min(p0, p1);
        #pragma unroll
        for (int off=32; off>=1; off>>=1) mm = u64min(mm, u64_shfl_down(mm, off));
        unsigned long long win = u64_bcast0(mm);
        if (lane==0) knn_idx[(size_t)q*16 + r] = (int)(win & 0xFFFFFFFFull);
        if (p0 == win) p0 = 0xFFFFFFFFFFFFFFFFull;
        if (p1 == win) p1 = 0xFFFFFFFFFFFFFFFFull;
    }
}

// ===================== k_group_local =====================
// grouped MLP + maxpool. One wave per query, lane = output channel.
// v3: weight chunks hoisted to REGISTERS across the k-loop (wt LDS reads
// 2048 -> 192 per wave); gd staged once per wave, read as float4 broadcasts.
template<int K, int NQ, int NSRC, bool RECOMP>
__global__ __launch_bounds__(256, 2) void k_group_local(
    const float* __restrict__ xyz, const float* __restrict__ f, const float* __restrict__ center,
    const float* __restrict__ conv1_w, const float* __restrict__ bn1_g, const float* __restrict__ bn1_b,
    const float* __restrict__ src_feat,
    const int* __restrict__ knn_idx, const float* __restrict__ np_feat,
    const float* __restrict__ w, const float* __restrict__ g, const float* __restrict__ bb,
    float* __restrict__ out)
{
    __shared__ float wt[128*65];          // wt[d*65+o] = w[o*128+d]; bank = (d+o)%32
    __shared__ float s_sc[64], s_bs[64];
    __shared__ float cwT[6*64];
    __shared__ float s_csc[64], s_cbs[64];
    __shared__ float np_l[4][64];
    __shared__ float gda[4][K][64];       // per-wave neighbor-diff features (16B aligned)
    __shared__ float s_pts[4][K][6];

    int t = threadIdx.x;
    for (int e=t; e<8192; e+=256){ int o = e>>7, d = e&127; wt[d*65 + o] = w[e]; }
    if (t < 64){ s_sc[t] = bnscale(g[t]); s_bs[t] = bb[t]; }
    if constexpr (RECOMP){
        for (int e=t; e<384; e+=256){ int o = e/6, j = e%6; cwT[j*64 + o] = conv1_w[e]; }
        if (t < 64){ s_csc[t] = bnscale(bn1_g[t]); s_cbs[t] = bn1_b[t]; }
    }
    __syncthreads();

    int wid = t>>6, lane = t&63;
    int q = blockIdx.x*4 + wid;
    int b = q / NQ, s = q % NQ;

    float np_o = np_feat[((size_t)b*NQ + s)*64 + lane];
    np_l[wid][lane] = np_o;

    const int* kix = knn_idx + ((size_t)b*NQ + s)*K;

    // ---- stage neighbor-diff features into gda[wid][k][lane] ----
    if constexpr (RECOMP){
        float cx = center[b*3+0], cy = center[b*3+1], cz = center[b*3+2];
        if (lane < K){
            int myi = kix[lane];
            const float* xp = xyz + ((size_t)b*16384 + myi)*3;
            s_pts[wid][lane][0] = xp[0]-cx;
            s_pts[wid][lane][1] = xp[1]-cy;
            s_pts[wid][lane][2] = xp[2]-cz;
            const float* fp = f + ((size_t)b*16384 + myi)*3;
            s_pts[wid][lane][3] = fp[0];
            s_pts[wid][lane][4] = fp[1];
            s_pts[wid][lane][5] = fp[2];
        }
        #pragma unroll
        for (int k=0; k<K; ++k){
            float gv = conv_feat6(s_pts[wid][k][0], s_pts[wid][k][1], s_pts[wid][k][2],
                                  s_pts[wid][k][3], s_pts[wid][k][4], s_pts[wid][k][5],
                                  cwT[0*64+lane], cwT[1*64+lane], cwT[2*64+lane],
                                  cwT[3*64+lane], cwT[4*64+lane], cwT[5*64+lane],
                                  s_csc[lane], s_cbs[lane]);
            gda[wid][k][lane] = gv - np_o;
        }
    } else {
        int myi = kix[lane < K ? lane : 0];
        #pragma unroll
        for (int k=0; k<K; ++k){
            int ik = __shfl(myi, k, 64);
            gda[wid][k][lane] = src_feat[((size_t)b*NSRC + ik)*64 + lane] - np_o;
        }
    }

    // ---- rep-term C (once per wave) ----
    float C = 0.f;
    #pragma unroll
    for (int d=0; d<64; d++) C = fmaf(np_l[wid][d], wt[(64+d)*65 + lane], C);

    float acc_y[K];
    #pragma unroll
    for (int k=0;k<K;k++) acc_y[k] = C;

    // ---- k-part: d-chunks of 32, weight chunk in registers across all k ----
    #pragma unroll
    for (int c=0; c<2; ++c){
        float wr[32];
        #pragma unroll
        for (int j=0;j<32;j++) wr[j] = wt[(c*32+j)*65 + lane];
        #pragma unroll
        for (int k=0;k<K;k++){
            const float4* g4 = (const float4*)&gda[wid][k][c*32];
            float yk = 0.f;
            #pragma unroll
            for (int j4=0;j4<8;j4++){
                float4 gg = g4[j4];
                yk = fmaf(gg.x, wr[j4*4+0], yk);
                yk = fmaf(gg.y, wr[j4*4+1], yk);
                yk = fmaf(gg.z, wr[j4*4+2], yk);
                yk = fmaf(gg.w, wr[j4*4+3], yk);
            }
            acc_y[k] = acc_y[k] + yk;
        }
    }

    float acc = -1e30f;
    #pragma unroll
    for (int k=0;k<K;k++){
        float v = fmaxf(fmaf(acc_y[k], s_sc[lane], s_bs[lane]), 0.0f);
        acc = fmaxf(acc, v);
    }
    out[((size_t)b*NQ + s)*64 + lane] = acc;
}

// ===================== k_tail =====================
__device__ void sa_block(const float* X, float* Xout,
                         float* Q, float* E, float* XV, float* XR, float* CS,
                         const float* qk_w, const float* v_w, const float* v_b,
                         const float* t_w, const float* t_b,
                         const float* g, const float* bb, int t)
{
    for (int e=t; e<512; e+=256){
        int n = e>>4, o = e&15;
        float y = 0.f;
        for (int c=0;c<64;c++) y = fmaf(qk_w[o*64+c], X[c*32+n], y);
        Q[n*16+o] = y;
    }
    for (int e=t; e<2048; e+=256){
        int o = e>>5, n = e&31;
        float y = v_b[o];
        for (int c=0;c<64;c++) y = fmaf(v_w[o*64+c], X[c*32+n], y);
        XV[o*32+n] = y;
    }
    __syncthreads();
    for (int e=t; e<1024; e+=256){
        int n = e>>5, m = e&31;
        float y = 0.f;
        for (int d=0;d<16;d++) y = fmaf(Q[n*16+d], Q[m*16+d], y);
        E[e] = y;
    }
    __syncthreads();
    if (t < 32){
        float mx = -1e30f;
        for (int m=0;m<32;m++) mx = fmaxf(mx, E[t*32+m]);
        float sum = 0.f;
        for (int m=0;m<32;m++){ float v = expf(E[t*32+m]-mx); E[t*32+m]=v; sum += v; }
        for (int m=0;m<32;m++) E[t*32+m] = E[t*32+m] / sum;
    }
    __syncthreads();
    if (t < 32){
        float cs = 0.f;
        for (int n=0;n<32;n++) cs += E[n*32+t];
        CS[t] = 1e-9f + cs;
    }
    __syncthreads();
    for (int e=t; e<1024; e+=256) E[e] = E[e] / CS[e&31];
    __syncthreads();
    for (int e=t; e<2048; e+=256){
        int c = e>>5, m = e&31;
        float y = 0.f;
        for (int n=0;n<32;n++) y = fmaf(XV[c*32+n], E[n*32+m], y);
        XR[c*32+m] = y;
    }
    __syncthreads();
    for (int e=t; e<2048; e+=256){
        int o = e>>5, n = e&31;
        float y = 0.f;
        for (int c=0;c<64;c++) y = fmaf(t_w[o*64+c], X[c*32+n]-XR[c*32+n], y);
        y += t_b[o];
        y = fmaxf(fmaf(y, bnscale(g[o]), bb[o]), 0.0f);
        Xout[e] = X[e] + y;
    }
    __syncthreads();
}

__global__ __launch_bounds__(256) void k_tail(
    const float* __restrict__ f1buf,
    const float* st_c1_w, const float* st_bn1_g, const float* st_bn1_b,
    const float* st_c2_w, const float* st_bn2_g, const float* st_bn2_b,
    const float* sa1_qk, const float* sa1_v, const float* sa1_vb,
    const float* sa1_t, const float* sa1_tb, const float* sa1_g, const float* sa1_b,
    const float* sa2_qk, const float* sa2_v, const float* sa2_vb,
    const float* sa2_t, const float* sa2_tb, const float* sa2_g, const float* sa2_b,
    const float* fuse_w, const float* fuse_g, const float* fuse_b,
    const float* lin1_w, const float* bn6_g, const float* bn6_b,
    const float* lin2_w, const float* lin2_b,
    float* __restrict__ out)
{
    __shared__ float sm[14848];
    float* F1 = sm;
    float* XA = sm + 2048;
    float* XB = sm + 4096;
    float* Q  = sm + 6144;
    float* E  = sm + 6656;
    float* XV = sm + 7680;
    float* XR = sm + 9728;
    float* CS = sm + 11776;
    float* FO = sm + 6144;
    float* PO = sm + 14336;
    float* P2 = sm + 14592;

    int b = blockIdx.x, t = threadIdx.x;

    for (int e=t; e<2048; e+=256){ int n = e>>6, c = e&63; F1[c*32+n] = f1buf[((size_t)b*32+n)*64 + c]; }
    __syncthreads();
    for (int e=t; e<2048; e+=256){
        int o = e>>5, n = e&31;
        float y = 0.f;
        for (int c=0;c<64;c++) y = fmaf(st_c1_w[o*64+c], F1[c*32+n], y);
        XA[e] = fmaxf(fmaf(y, bnscale(st_bn1_g[o]), st_bn1_b[o]), 0.0f);
    }
    __syncthreads();
    for (int e=t; e<2048; e+=256){
        int o = e>>5, n = e&31;
        float y = 0.f;
        for (int c=0;c<64;c++) y = fmaf(st_c2_w[o*64+c], XA[c*32+n], y);
        XB[e] = fmaxf(fmaf(y, bnscale(st_bn2_g[o]), st_bn2_b[o]), 0.0f);
    }
    __syncthreads();
    sa_block(XB, XA, Q,E,XV,XR,CS, sa1_qk, sa1_v, sa1_vb, sa1_t, sa1_tb, sa1_g, sa1_b, t);
    sa_block(XA, XB, Q,E,XV,XR,CS, sa2_qk, sa2_v, sa2_vb, sa2_t, sa2_tb, sa2_g, sa2_b, t);
    for (int e=t; e<8192; e+=256){
        int o = e>>5, n = e&31;
        const float* wr = fuse_w + o*192;
        float y = 0.f;
        for (int c=0;c<64;c++) y = fmaf(wr[c],      XA[c*32+n], y);
        for (int c=0;c<64;c++) y = fmaf(wr[64+c],   XB[c*32+n], y);
        for (int c=0;c<64;c++) y = fmaf(wr[128+c],  F1[c*32+n], y);
        float v = fmaf(y, bnscale(fuse_g[o]), fuse_b[o]);
        FO[e] = (v > 0.0f) ? v : 0.2f*v;
    }
    __syncthreads();
    {
        float mx = -1e30f;
        for (int n=0;n<32;n++) mx = fmaxf(mx, FO[t*32+n]);
        PO[t] = mx;
    }
    __syncthreads();
    {
        const float* wr = lin1_w + t*256;
        float y = 0.f;
        for (int c=0;c<256;c++) y = fmaf(wr[c], PO[c], y);
        P2[t] = fmaxf(fmaf(y, bnscale(bn6_g[t]), bn6_b[t]), 0.0f);
    }
    __syncthreads();
    {
        const float* wr = lin2_w + t*256;
        float y = 0.f;
        for (int c=0;c<256;c++) y = fmaf(wr[c], P2[c], y);
        out[96 + b*256 + t] = y + lin2_b[t];
    }
}

// ===================== launch =====================
extern "C" void kernel_launch(void* const* d_in, const int* in_sizes, int n_in,
                              void* d_out, int out_size, void* d_ws, size_t ws_size,
                              hipStream_t stream)
{
    const float* xyz      = (const float*)d_in[0];
    const float* f        = (const float*)d_in[1];
    const float* conv1_w  = (const float*)d_in[2];
    const float* bn1_g    = (const float*)d_in[3];
    const float* bn1_b    = (const float*)d_in[4];
    const float* l0_w     = (const float*)d_in[5];
    const float* l0_g     = (const float*)d_in[6];
    const float* l0_b     = (const float*)d_in[7];
    const float* l1_w     = (const float*)d_in[8];
    const float* l1_g     = (const float*)d_in[9];
    const float* l1_b     = (const float*)d_in[10];
    const float* st_c1_w  = (const float*)d_in[11];
    const float* st_bn1_g = (const float*)d_in[12];
    const float* st_bn1_b = (const float*)d_in[13];
    const float* st_c2_w  = (const float*)d_in[14];
    const float* st_bn2_g = (const float*)d_in[15];
    const float* st_bn2_b = (const float*)d_in[16];
    const float* sa1_qk   = (const float*)d_in[17];
    const float* sa1_v    = (const float*)d_in[18];
    const float* sa1_vb   = (const float*)d_in[19];
    const float* sa1_t    = (const float*)d_in[20];
    const float* sa1_tb   = (const float*)d_in[21];
    const float* sa1_g    = (const float*)d_in[22];
    const float* sa1_b    = (const float*)d_in[23];
    const float* sa2_qk   = (const float*)d_in[24];
    const float* sa2_v    = (const float*)d_in[25];
    const float* sa2_vb   = (const float*)d_in[26];
    const float* sa2_t    = (const float*)d_in[27];
    const float* sa2_tb   = (const float*)d_in[28];
    const float* sa2_g    = (const float*)d_in[29];
    const float* sa2_b    = (const float*)d_in[30];
    const float* fuse_w   = (const float*)d_in[31];
    const float* fuse_g   = (const float*)d_in[32];
    const float* fuse_b   = (const float*)d_in[33];
    const float* lin1_w   = (const float*)d_in[34];
    const float* bn6_g    = (const float*)d_in[35];
    const float* bn6_b    = (const float*)d_in[36];
    const float* lin2_w   = (const float*)d_in[37];
    const float* lin2_b   = (const float*)d_in[38];
    float* out = (float*)d_out;

    float* ws = (float*)d_ws;
    float* center   = ws + 0;        // 96
    float* new_xyz1 = ws + 96;       // 12288
    float* np1      = ws + 12384;    // 262144
    float* feat     = ws + 274528;   // 262144
    float* new_xyz2 = ws + 536672;   // 3072
    float* np2      = ws + 539744;   // 65536
    float* f1       = ws + 605280;   // 65536
    int*   fps1     = (int*)(ws + 670816);  // 4096
    int*   knn1     = (int*)(ws + 674912);  // 131072
    int*   fps2     = (int*)(ws + 805984);  // 1024
    int*   knn2     = (int*)(ws + 807008);  // 16384

    k_fps1<<<32, 512, 0, stream>>>(xyz, center, out, fps1);
    k_gather1<<<4096, 64, 0, stream>>>(xyz, f, center, conv1_w, bn1_g, bn1_b, fps1, new_xyz1, np1);
    k_knn1<<<4096, 256, 0, stream>>>(xyz, center, new_xyz1, knn1);
    k_group_local<32,128,1,true><<<1024, 256, 0, stream>>>(
        xyz, f, center, conv1_w, bn1_g, bn1_b, nullptr, knn1, np1, l0_w, l0_g, l0_b, feat);
    k_fps2<<<32, 64, 0, stream>>>(new_xyz1, fps2);
    k_gather2<<<1024, 64, 0, stream>>>(new_xyz1, feat, fps2, new_xyz2, np2);
    k_knn2<<<256, 256, 0, stream>>>(new_xyz1, new_xyz2, knn2);
    k_group_local<16,32,128,false><<<256, 256, 0, stream>>>(
        nullptr, nullptr, nullptr, nullptr, nullptr, nullptr, feat, knn2, np2, l1_w, l1_g, l1_b, f1);
    k_tail<<<32, 256, 0, stream>>>(f1,
        st_c1_w, st_bn1_g, st_bn1_b, st_c2_w, st_bn2_g, st_bn2_b,
        sa1_qk, sa1_v, sa1_vb, sa1_t, sa1_tb, sa1_g, sa1_b,
        sa2_qk, sa2_v, sa2_vb, sa2_t, sa2_tb, sa2_g, sa2_b,
        fuse_w, fuse_g, fuse_b, lin1_w, bn6_g, bn6_b, lin2_w, lin2_b, out);
}